// Round 1
// baseline (436.481 us; speedup 1.0000x reference)
//
#include <hip/hip_runtime.h>
#include <hip/hip_bf16.h>

#define SEQ   8192
#define DIN   256
#define DOUT  64
// log2(e) / sqrt(DOUT) folded into q at projection time -> softmax in exp2 domain
#define QSCALE 0.1803368801111204f

__device__ __forceinline__ float exp2f_fast(float x) { return __builtin_amdgcn_exp2f(x); }

// ---------------- QKV projection ----------------
// grid 256 blocks x 256 threads; each block: 32 x-rows, all 192 output cols
// LDS: x staged transposed [d][r] (conflict-free reads), W staged 32-col halves.
__global__ __launch_bounds__(256) void qkv_kernel(
    const float* __restrict__ x, const float* __restrict__ wq,
    const float* __restrict__ wk, const float* __restrict__ wv,
    float* __restrict__ qo, float* __restrict__ ko, float* __restrict__ vo)
{
  __shared__ float  sxT[DIN * 32];   // 32 KB, [d][r]
  __shared__ float4 sw4[DIN * 8];    // 32 KB, [d][c8] (32 cols per phase)
  const int tid = threadIdx.x;
  const int r0  = blockIdx.x * 32;

  // stage x transposed: row-fastest assignment -> conflict-free LDS writes
  const float4* x4 = (const float4*)x;
  #pragma unroll
  for (int i = 0; i < 8; ++i) {
    int f4  = tid + 256 * i;       // 0..2047
    int row = f4 & 31;
    int d4  = f4 >> 5;             // 0..63
    float4 xv = x4[(size_t)(r0 + row) * 64 + d4];
    sxT[(d4 * 4 + 0) * 32 + row] = xv.x;
    sxT[(d4 * 4 + 1) * 32 + row] = xv.y;
    sxT[(d4 * 4 + 2) * 32 + row] = xv.z;
    sxT[(d4 * 4 + 3) * 32 + row] = xv.w;
  }

  const float* wmats[3] = {wq, wk, wv};
  float*       outs[3]  = {qo, ko, vo};
  const int r  = tid >> 3;   // 0..31
  const int cg = tid & 7;    // 0..7  -> 4 cols each

  for (int ph = 0; ph < 6; ++ph) {
    int mat = ph >> 1, ch = ph & 1;
    const float4* w4 = (const float4*)wmats[mat];
    #pragma unroll
    for (int i = 0; i < 8; ++i) {
      int f4 = tid + 256 * i;    // 0..2047
      int d  = f4 >> 3, c8 = f4 & 7;
      sw4[d * 8 + c8] = w4[d * 16 + ch * 8 + c8];
    }
    __syncthreads();
    float ax = 0.f, ay = 0.f, az = 0.f, aw = 0.f;
    for (int d = 0; d < DIN; ++d) {
      float  xv = sxT[d * 32 + r];
      float4 w  = sw4[d * 8 + cg];
      ax = fmaf(xv, w.x, ax); ay = fmaf(xv, w.y, ay);
      az = fmaf(xv, w.z, az); aw = fmaf(xv, w.w, aw);
    }
    if (mat == 0) { ax *= QSCALE; ay *= QSCALE; az *= QSCALE; aw *= QSCALE; }
    float4 res = {ax, ay, az, aw};
    *(float4*)(outs[mat] + (size_t)(r0 + r) * DOUT + ch * 32 + cg * 4) = res;
    __syncthreads();
  }
}

// ---------------- flash attention, split-K ----------------
// Layout A: each lane owns one q row (softmax lane-local). Block = 256 threads =
// 256 q rows; grid = (32, S). K/V tiles (64 rows) double-buffered in LDS,
// consumed via broadcast ds_read_b128. Deferred-rescale online softmax (log2 domain).
__global__ __launch_bounds__(256, 2) void attn_kernel(
    const float* __restrict__ q, const float* __restrict__ k, const float* __restrict__ v,
    float* __restrict__ opart, float2* __restrict__ mlpart, int slice_len)
{
  __shared__ float sbuf[2][64 * 64 * 2];  // [buf][ k-tile 4096 f | v-tile 4096 f ] = 64 KB
  const int tid   = threadIdx.x;
  const int row   = blockIdx.x * 256 + tid;
  const int split = blockIdx.y;
  const int j0    = split * slice_len;
  const int NT    = slice_len >> 6;

  float4 q4[16];
  const float4* qsrc = (const float4*)(q + (size_t)row * DOUT);
  #pragma unroll
  for (int c = 0; c < 16; ++c) q4[c] = qsrc[c];

  float4 o4[16];
  #pragma unroll
  for (int c = 0; c < 16; ++c) o4[c] = make_float4(0.f, 0.f, 0.f, 0.f);
  float m = -3.0e38f, l = 0.f;

  auto stage = [&](int t, int b) {
    const float4* kb = (const float4*)(k + (size_t)(j0 + t * 64) * DOUT);
    const float4* vb = (const float4*)(v + (size_t)(j0 + t * 64) * DOUT);
    float4* dst = (float4*)&sbuf[b][0];
    #pragma unroll
    for (int i = 0; i < 4; ++i) dst[tid + 256 * i] = kb[tid + 256 * i];
    #pragma unroll
    for (int i = 0; i < 4; ++i) dst[1024 + tid + 256 * i] = vb[tid + 256 * i];
  };

  stage(0, 0);
  __syncthreads();

  for (int t = 0; t < NT; ++t) {
    const int b = t & 1;
    if (t + 1 < NT) stage(t + 1, b ^ 1);
    const float4* kb = (const float4*)&sbuf[b][0];
    const float4* vb = (const float4*)&sbuf[b][4096];
    for (int j = 0; j < 64; ++j) {
      float s0 = 0.f, s1 = 0.f, s2 = 0.f, s3 = 0.f;
      #pragma unroll
      for (int c = 0; c < 16; ++c) {
        float4 kk = kb[j * 16 + c];
        s0 = fmaf(q4[c].x, kk.x, s0);
        s1 = fmaf(q4[c].y, kk.y, s1);
        s2 = fmaf(q4[c].z, kk.z, s2);
        s3 = fmaf(q4[c].w, kk.w, s3);
      }
      float sm = (s0 + s1) + (s2 + s3);   // already in log2 domain (QSCALE folded)
      if (sm > m + 60.0f) {               // rare deferred rescale
        float r = exp2f_fast(m - sm);
        #pragma unroll
        for (int c = 0; c < 16; ++c) {
          o4[c].x *= r; o4[c].y *= r; o4[c].z *= r; o4[c].w *= r;
        }
        l *= r; m = sm;
      }
      float p = exp2f_fast(sm - m);       // bounded by 2^60
      l += p;
      #pragma unroll
      for (int c = 0; c < 16; ++c) {
        float4 vv = vb[j * 16 + c];
        o4[c].x = fmaf(p, vv.x, o4[c].x);
        o4[c].y = fmaf(p, vv.y, o4[c].y);
        o4[c].z = fmaf(p, vv.z, o4[c].z);
        o4[c].w = fmaf(p, vv.w, o4[c].w);
      }
    }
    __syncthreads();
  }

  float4* od = (float4*)(opart + ((size_t)split * SEQ + row) * DOUT);
  #pragma unroll
  for (int c = 0; c < 16; ++c) od[c] = o4[c];
  mlpart[(size_t)split * SEQ + row] = make_float2(m, l);
}

// ---------------- combine split-K partials ----------------
__global__ __launch_bounds__(256) void combine_kernel(
    const float* __restrict__ opart, const float2* __restrict__ mlpart,
    float* __restrict__ out, int S)
{
  const int tid = threadIdx.x;
  const int row = blockIdx.x * 16 + (tid >> 4);
  const int c4  = tid & 15;
  float mstar = -3.0e38f;
  for (int i = 0; i < S; ++i)
    mstar = fmaxf(mstar, mlpart[(size_t)i * SEQ + row].x);
  float L = 0.f, ax = 0.f, ay = 0.f, az = 0.f, aw = 0.f;
  for (int i = 0; i < S; ++i) {
    float2 ml = mlpart[(size_t)i * SEQ + row];
    float  w  = exp2f_fast(ml.x - mstar);
    L = fmaf(w, ml.y, L);
    float4 ov = ((const float4*)(opart + ((size_t)i * SEQ + row) * DOUT))[c4];
    ax = fmaf(w, ov.x, ax); ay = fmaf(w, ov.y, ay);
    az = fmaf(w, ov.z, az); aw = fmaf(w, ov.w, aw);
  }
  float inv = 1.0f / L;
  float4 res = {ax * inv, ay * inv, az * inv, aw * inv};
  ((float4*)(out + (size_t)row * DOUT))[c4] = res;
}

extern "C" void kernel_launch(void* const* d_in, const int* in_sizes, int n_in,
                              void* d_out, int out_size, void* d_ws, size_t ws_size,
                              hipStream_t stream)
{
  const float* x  = (const float*)d_in[0];
  const float* wq = (const float*)d_in[1];
  const float* wk = (const float*)d_in[2];
  const float* wv = (const float*)d_in[3];
  float* out = (float*)d_out;

  float* q = (float*)d_ws;
  float* k = q + (size_t)SEQ * DOUT;
  float* v = k + (size_t)SEQ * DOUT;
  float* opart = v + (size_t)SEQ * DOUT;

  int S = 16;
  while (S > 1) {
    size_t need = ((size_t)3 * SEQ * DOUT + (size_t)S * SEQ * DOUT + (size_t)S * SEQ * 2) * 4;
    if (need <= ws_size) break;
    S >>= 1;
  }
  float2* mlpart = (float2*)(opart + (size_t)S * SEQ * DOUT);
  const int slice_len = SEQ / S;

  qkv_kernel<<<256, 256, 0, stream>>>(x, wq, wk, wv, q, k, v);
  attn_kernel<<<dim3(SEQ / 256, S), 256, 0, stream>>>(q, k, v, opart, mlpart, slice_len);
  combine_kernel<<<SEQ / 16, 256, 0, stream>>>(opart, mlpart, out, S);
}

// Round 2
// 154.166 us; speedup vs baseline: 2.8312x; 2.8312x over previous
//
#include <hip/hip_runtime.h>
#include <hip/hip_bf16.h>

#define SEQ   8192
#define DIN   256
#define DOUT  64
// log2(e) / sqrt(DOUT) folded into q at projection time -> softmax in exp2 domain
#define QSCALE 0.1803368801111204f

using bf16x8 = __attribute__((ext_vector_type(8))) short;   // 8 bf16 = 4 VGPR
using f32x16 = __attribute__((ext_vector_type(16))) float;  // MFMA 32x32 acc

__device__ __forceinline__ float exp2f_fast(float x) { return __builtin_amdgcn_exp2f(x); }

__device__ __forceinline__ f32x16 mfma32(bf16x8 a, bf16x8 b, f32x16 c) {
  return __builtin_amdgcn_mfma_f32_32x32x16_bf16(a, b, c, 0, 0, 0);
}

// round-to-nearest-even fp32 -> bf16 bits
__device__ __forceinline__ unsigned f2bfbits(float f) {
  unsigned u = __builtin_bit_cast(unsigned, f);
  return (u + 0x7fffu + ((u >> 16) & 1u)) >> 16;
}
__device__ __forceinline__ unsigned pkb(float a, float b) {
  return f2bfbits(a) | (f2bfbits(b) << 16);
}
__device__ __forceinline__ float bfhi_f(float v) {           // value of bf16(v)
  return __builtin_bit_cast(float, f2bfbits(v) << 16);
}

// ---------------- QKV projection ----------------
// 256 blocks x 256 threads; block: 32 x-rows, all 192 output cols.
// Writes q,k as bf16 hi/lo split (q pre-scaled by QSCALE), v as fp32.
__global__ __launch_bounds__(256) void qkv_kernel(
    const float* __restrict__ x, const float* __restrict__ wq,
    const float* __restrict__ wk, const float* __restrict__ wv,
    unsigned short* __restrict__ qhi, unsigned short* __restrict__ qlo,
    unsigned short* __restrict__ khi, unsigned short* __restrict__ klo,
    float* __restrict__ vo)
{
  __shared__ float  sxT[DIN * 32];   // 32 KB, [d][r]
  __shared__ float4 sw4[DIN * 8];    // 32 KB, [d][c8]
  const int tid = threadIdx.x;
  const int r0  = blockIdx.x * 32;

  const float4* x4 = (const float4*)x;
  #pragma unroll
  for (int i = 0; i < 8; ++i) {
    int f4  = tid + 256 * i;
    int row = f4 & 31;
    int d4  = f4 >> 5;
    float4 xv = x4[(size_t)(r0 + row) * 64 + d4];
    sxT[(d4 * 4 + 0) * 32 + row] = xv.x;
    sxT[(d4 * 4 + 1) * 32 + row] = xv.y;
    sxT[(d4 * 4 + 2) * 32 + row] = xv.z;
    sxT[(d4 * 4 + 3) * 32 + row] = xv.w;
  }

  const float* wmats[3] = {wq, wk, wv};
  const int r  = tid >> 3;   // 0..31
  const int cg = tid & 7;    // 0..7

  for (int ph = 0; ph < 6; ++ph) {
    int mat = ph >> 1, ch = ph & 1;
    const float4* w4 = (const float4*)wmats[mat];
    #pragma unroll
    for (int i = 0; i < 8; ++i) {
      int f4 = tid + 256 * i;
      int d  = f4 >> 3, c8 = f4 & 7;
      sw4[d * 8 + c8] = w4[d * 16 + ch * 8 + c8];
    }
    __syncthreads();
    float acc[4] = {0.f, 0.f, 0.f, 0.f};
    for (int d = 0; d < DIN; ++d) {
      float  xv = sxT[d * 32 + r];
      float4 w  = sw4[d * 8 + cg];
      acc[0] = fmaf(xv, w.x, acc[0]); acc[1] = fmaf(xv, w.y, acc[1]);
      acc[2] = fmaf(xv, w.z, acc[2]); acc[3] = fmaf(xv, w.w, acc[3]);
    }
    size_t base = (size_t)(r0 + r) * DOUT + ch * 32 + cg * 4;
    if (mat < 2) {
      if (mat == 0) { acc[0]*=QSCALE; acc[1]*=QSCALE; acc[2]*=QSCALE; acc[3]*=QSCALE; }
      ushort4 hv, lv;
      unsigned short* hp = (unsigned short*)&hv;
      unsigned short* lp = (unsigned short*)&lv;
      #pragma unroll
      for (int j = 0; j < 4; ++j) {
        unsigned hb = f2bfbits(acc[j]);
        hp[j] = (unsigned short)hb;
        float fh = __builtin_bit_cast(float, hb << 16);
        lp[j] = (unsigned short)f2bfbits(acc[j] - fh);
      }
      unsigned short* hdst = mat ? khi : qhi;
      unsigned short* ldst = mat ? klo : qlo;
      *(ushort4*)&hdst[base] = hv;
      *(ushort4*)&ldst[base] = lv;
    } else {
      float4 res = {acc[0], acc[1], acc[2], acc[3]};
      *(float4*)&vo[base] = res;
    }
    __syncthreads();
  }
}

// ---------------- V transpose + bf16 hi/lo split ----------------
// v [SEQ][64] fp32 -> vThi/vTlo [64][SEQ] bf16
__global__ __launch_bounds__(256) void vtrans_kernel(
    const float* __restrict__ v,
    unsigned short* __restrict__ vThi, unsigned short* __restrict__ vTlo)
{
  __shared__ float t[64][65];
  const int tid = threadIdx.x;
  const int r0  = blockIdx.x * 64;
  #pragma unroll
  for (int i = 0; i < 4; ++i) {
    int flat = tid + 256 * i;        // 0..1023
    int row = flat >> 4;             // 0..63
    int c4  = flat & 15;
    float4 w = *(const float4*)&v[(size_t)(r0 + row) * 64 + c4 * 4];
    t[row][c4 * 4 + 0] = w.x; t[row][c4 * 4 + 1] = w.y;
    t[row][c4 * 4 + 2] = w.z; t[row][c4 * 4 + 3] = w.w;
  }
  __syncthreads();
  #pragma unroll
  for (int i = 0; i < 2; ++i) {
    int flat = tid + 256 * i;        // 0..511
    int d   = flat >> 3;             // 0..63
    int seg = flat & 7;
    ushort4 h0, h1, l0, l1;
    unsigned short* hp0 = (unsigned short*)&h0; unsigned short* hp1 = (unsigned short*)&h1;
    unsigned short* lp0 = (unsigned short*)&l0; unsigned short* lp1 = (unsigned short*)&l1;
    #pragma unroll
    for (int j = 0; j < 8; ++j) {
      float val = t[seg * 8 + j][d];
      unsigned hb = f2bfbits(val);
      float fh = __builtin_bit_cast(float, hb << 16);
      unsigned lb = f2bfbits(val - fh);
      if (j < 4) { hp0[j] = (unsigned short)hb; lp0[j] = (unsigned short)lb; }
      else       { hp1[j-4] = (unsigned short)hb; lp1[j-4] = (unsigned short)lb; }
    }
    size_t base = (size_t)d * SEQ + r0 + seg * 8;
    *(ushort4*)&vThi[base]     = h0;
    *(ushort4*)&vThi[base + 4] = h1;
    *(ushort4*)&vTlo[base]     = l0;
    *(ushort4*)&vTlo[base + 4] = l1;
  }
}

// ---------------- MFMA flash attention, split-K ----------------
// 8 warps x 32 q-rows = 256 q-rows/block. KVBLK=64 double-buffered in LDS
// (XOR-swizzled, 64 KB). Swapped QK^T (mfma(K,Q)) so each lane owns one
// q-row: softmax is in-lane + one shfl_xor(32). QK in bf16x3, PV: P bf16,
// V bf16x2. Deferred-max online softmax in exp2 domain.
__global__ __launch_bounds__(512, 2) void attn_mfma_kernel(
    const unsigned short* __restrict__ qhi, const unsigned short* __restrict__ qlo,
    const unsigned short* __restrict__ khi, const unsigned short* __restrict__ klo,
    const unsigned short* __restrict__ vThi, const unsigned short* __restrict__ vTlo,
    float* __restrict__ opart, float2* __restrict__ mlpart, int slice_len)
{
  // [buf][arr: 0=Khi 1=Klo 2=VThi 3=VTlo][64*64] bf16, 16B-slot XOR swizzle
  __shared__ unsigned short sm[2][4][4096];   // 65536 B
  const int tid  = threadIdx.x;
  const int lane = tid & 63;
  const int w    = tid >> 6;          // warp 0..7
  const int qr   = lane & 31;         // q column within warp tile
  const int h    = lane >> 5;         // half
  const int split = blockIdx.y;
  const int j0   = split * slice_len;
  const int qg   = blockIdx.x * 256 + w * 32 + qr;
  const int NT   = slice_len >> 6;

  // Q fragments in registers: chunk c covers d = 16c + 8h + 0..7
  bf16x8 qh[4], ql[4];
  #pragma unroll
  for (int c = 0; c < 4; ++c) {
    qh[c] = *(const bf16x8*)&qhi[(size_t)qg * 64 + 16 * c + 8 * h];
    ql[c] = *(const bf16x8*)&qlo[(size_t)qg * 64 + 16 * c + 8 * h];
  }

  f32x16 o0, o1;
  #pragma unroll
  for (int i = 0; i < 16; ++i) { o0[i] = 0.f; o1[i] = 0.f; }
  float m = -1.0e30f, l = 0.f;

  // staging: thread -> (row tid>>3, 16B seg tid&7), swizzled slot
  const int srow = tid >> 3, sseg = tid & 7;
  const int soff = srow * 64 + ((sseg ^ (srow & 7)) << 3);

  bf16x8 st[4];
  {
    size_t kr  = (size_t)(j0 + srow);
    size_t col = (size_t)(j0 + sseg * 8);
    st[0] = *(const bf16x8*)&khi[kr * 64 + sseg * 8];
    st[1] = *(const bf16x8*)&klo[kr * 64 + sseg * 8];
    st[2] = *(const bf16x8*)&vThi[(size_t)srow * SEQ + col];
    st[3] = *(const bf16x8*)&vTlo[(size_t)srow * SEQ + col];
    #pragma unroll
    for (int a = 0; a < 4; ++a) *(bf16x8*)&sm[0][a][soff] = st[a];
  }
  __syncthreads();

  for (int t = 0; t < NT; ++t) {
    const int b = t & 1;
    bf16x8 nx[4];
    if (t + 1 < NT) {                       // async-stage: issue loads early
      size_t kr  = (size_t)(j0 + (t + 1) * 64 + srow);
      size_t col = (size_t)(j0 + (t + 1) * 64 + sseg * 8);
      nx[0] = *(const bf16x8*)&khi[kr * 64 + sseg * 8];
      nx[1] = *(const bf16x8*)&klo[kr * 64 + sseg * 8];
      nx[2] = *(const bf16x8*)&vThi[(size_t)srow * SEQ + col];
      nx[3] = *(const bf16x8*)&vTlo[(size_t)srow * SEQ + col];
    }
    const unsigned short* KH = &sm[b][0][0];
    const unsigned short* KL = &sm[b][1][0];
    const unsigned short* VH = &sm[b][2][0];
    const unsigned short* VL = &sm[b][3][0];

    // ---- S^T = K . Q^T  (bf16x3), tiles: kr 0..31 (s0), 32..63 (s1)
    f32x16 s0, s1;
    #pragma unroll
    for (int i = 0; i < 16; ++i) { s0[i] = 0.f; s1[i] = 0.f; }
    #pragma unroll
    for (int c = 0; c < 4; ++c) {
      int slot = (2 * c + h) ^ (qr & 7);
      int a0 = qr * 64 + slot * 8;
      int a1 = a0 + 32 * 64;
      bf16x8 kh0 = *(const bf16x8*)&KH[a0];
      bf16x8 kh1 = *(const bf16x8*)&KH[a1];
      bf16x8 kl0 = *(const bf16x8*)&KL[a0];
      bf16x8 kl1 = *(const bf16x8*)&KL[a1];
      s0 = mfma32(kh0, qh[c], s0);
      s1 = mfma32(kh1, qh[c], s1);
      s0 = mfma32(kl0, qh[c], s0);
      s1 = mfma32(kl1, qh[c], s1);
      s0 = mfma32(kh0, ql[c], s0);
      s1 = mfma32(kh1, ql[c], s1);
    }

    // ---- online softmax (log2 domain); lane holds 32 scores of row qg
    float pm = s0[0];
    #pragma unroll
    for (int i = 1; i < 16; ++i) pm = fmaxf(pm, s0[i]);
    #pragma unroll
    for (int i = 0; i < 16; ++i) pm = fmaxf(pm, s1[i]);
    pm = fmaxf(pm, __shfl_xor(pm, 32));

    bool need = (pm > m + 40.0f);
    if (__any(need)) {
      float nm = fmaxf(m, pm);
      float r  = exp2f_fast(m - nm);
      #pragma unroll
      for (int i = 0; i < 16; ++i) { o0[i] *= r; o1[i] *= r; }
      l *= r; m = nm;
    }
    #pragma unroll
    for (int i = 0; i < 16; ++i) { s0[i] = exp2f_fast(s0[i] - m); }
    #pragma unroll
    for (int i = 0; i < 16; ++i) { s1[i] = exp2f_fast(s1[i] - m); }
    float ls = 0.f;
    #pragma unroll
    for (int i = 0; i < 16; ++i) ls += s0[i];
    #pragma unroll
    for (int i = 0; i < 16; ++i) ls += s1[i];
    l += ls + __shfl_xor(ls, 32);

    // ---- build P^T B-frags (k = kr): frag[kc], kc = ti*2+c covers kr 16kc+8h+0..7
    unsigned fw[4][4];
    #pragma unroll
    for (int ti = 0; ti < 2; ++ti) {
      #pragma unroll
      for (int c = 0; c < 2; ++c) {
        const f32x16& S = ti ? s1 : s0;
        unsigned X0 = pkb(S[8*c+0], S[8*c+1]);   // group g=2c   (kr 16c+4h+0..3 pairs)
        unsigned Y0 = pkb(S[8*c+2], S[8*c+3]);
        unsigned X1 = pkb(S[8*c+4], S[8*c+5]);   // group g=2c+1
        unsigned Y1 = pkb(S[8*c+6], S[8*c+7]);
        unsigned rX0 = __shfl_xor(X0, 32);
        unsigned rY0 = __shfl_xor(Y0, 32);
        unsigned rX1 = __shfl_xor(X1, 32);
        unsigned rY1 = __shfl_xor(Y1, 32);
        fw[ti*2+c][0] = h ? rX1 : X0;
        fw[ti*2+c][1] = h ? rY1 : Y0;
        fw[ti*2+c][2] = h ? X1  : rX0;
        fw[ti*2+c][3] = h ? Y1  : rY0;
      }
    }

    // ---- O^T += V^T . P^T   (V in bf16x2)
    #pragma unroll
    for (int dt = 0; dt < 2; ++dt) {
      f32x16& O = dt ? o1 : o0;
      #pragma unroll
      for (int kc = 0; kc < 4; ++kc) {
        int slot = (2 * kc + h) ^ (qr & 7);
        int addr = (qr + 32 * dt) * 64 + slot * 8;
        uint4 u = {fw[kc][0], fw[kc][1], fw[kc][2], fw[kc][3]};
        bf16x8 pf = __builtin_bit_cast(bf16x8, u);
        bf16x8 vh = *(const bf16x8*)&VH[addr];
        bf16x8 vl = *(const bf16x8*)&VL[addr];
        O = mfma32(vh, pf, O);
        O = mfma32(vl, pf, O);
      }
    }

    __syncthreads();
    if (t + 1 < NT) {
      #pragma unroll
      for (int a = 0; a < 4; ++a) *(bf16x8*)&sm[b ^ 1][a][soff] = nx[a];
    }
    __syncthreads();
  }

  // ---- epilogue: O^T regs -> opart rows; d = a + 8b + 4h (+32 for tile1)
  const size_t obase = ((size_t)split * SEQ + qg) * 64;
  #pragma unroll
  for (int b2 = 0; b2 < 4; ++b2) {
    int d0 = 8 * b2 + 4 * h;
    float4 w0 = {o0[4*b2+0], o0[4*b2+1], o0[4*b2+2], o0[4*b2+3]};
    *(float4*)&opart[obase + d0] = w0;
    float4 w1 = {o1[4*b2+0], o1[4*b2+1], o1[4*b2+2], o1[4*b2+3]};
    *(float4*)&opart[obase + 32 + d0] = w1;
  }
  if (h == 0) mlpart[(size_t)split * SEQ + qg] = make_float2(m, l);
}

// ---------------- combine split-K partials ----------------
__global__ __launch_bounds__(256) void combine_kernel(
    const float* __restrict__ opart, const float2* __restrict__ mlpart,
    float* __restrict__ out, int S)
{
  const int tid = threadIdx.x;
  const int row = blockIdx.x * 16 + (tid >> 4);
  const int c4  = tid & 15;
  float mstar = -3.0e38f;
  for (int i = 0; i < S; ++i)
    mstar = fmaxf(mstar, mlpart[(size_t)i * SEQ + row].x);
  float L = 0.f, ax = 0.f, ay = 0.f, az = 0.f, aw = 0.f;
  for (int i = 0; i < S; ++i) {
    float2 ml = mlpart[(size_t)i * SEQ + row];
    float  wgt = exp2f_fast(ml.x - mstar);
    L = fmaf(wgt, ml.y, L);
    float4 ov = ((const float4*)(opart + ((size_t)i * SEQ + row) * DOUT))[c4];
    ax = fmaf(wgt, ov.x, ax); ay = fmaf(wgt, ov.y, ay);
    az = fmaf(wgt, ov.z, az); aw = fmaf(wgt, ov.w, aw);
  }
  float inv = 1.0f / L;
  float4 res = {ax * inv, ay * inv, az * inv, aw * inv};
  ((float4*)(out + (size_t)row * DOUT))[c4] = res;
}

extern "C" void kernel_launch(void* const* d_in, const int* in_sizes, int n_in,
                              void* d_out, int out_size, void* d_ws, size_t ws_size,
                              hipStream_t stream)
{
  const float* x  = (const float*)d_in[0];
  const float* wq = (const float*)d_in[1];
  const float* wk = (const float*)d_in[2];
  const float* wv = (const float*)d_in[3];
  float* out = (float*)d_out;

  char* ws = (char*)d_ws;
  const size_t MB = (size_t)SEQ * DOUT * 2;   // 1 MB per bf16 array
  unsigned short* qhi  = (unsigned short*)(ws);
  unsigned short* qlo  = (unsigned short*)(ws + MB);
  unsigned short* khi  = (unsigned short*)(ws + 2 * MB);
  unsigned short* klo  = (unsigned short*)(ws + 3 * MB);
  unsigned short* vThi = (unsigned short*)(ws + 4 * MB);
  unsigned short* vTlo = (unsigned short*)(ws + 5 * MB);
  float* vf32  = (float*)(ws + 6 * MB);                       // 2 MB
  float* opart = (float*)(ws + 8 * MB);

  int S = 16;
  while (S > 1) {
    size_t need = 8 * MB + ((size_t)S * SEQ * DOUT + (size_t)S * SEQ * 2) * 4;
    if (need <= ws_size) break;
    S >>= 1;
  }
  float2* mlpart = (float2*)(opart + (size_t)S * SEQ * DOUT);
  const int slice_len = SEQ / S;

  qkv_kernel<<<256, 256, 0, stream>>>(x, wq, wk, wv, qhi, qlo, khi, klo, vf32);
  vtrans_kernel<<<SEQ / 64, 256, 0, stream>>>(vf32, vThi, vTlo);
  attn_mfma_kernel<<<dim3(SEQ / 256, S), 512, 0, stream>>>(
      qhi, qlo, khi, klo, vThi, vTlo, opart, mlpart, slice_len);
  combine_kernel<<<SEQ / 16, 256, 0, stream>>>(opart, mlpart, out, S);
}

// Round 4
// 132.392 us; speedup vs baseline: 3.2969x; 1.1645x over previous
//
#include <hip/hip_runtime.h>
#include <hip/hip_bf16.h>

#define SEQ   8192
#define DIN   256
#define DOUT  64
// log2(e)/sqrt(DOUT) folded into q -> softmax in exp2 domain
#define QSCALE 0.1803368801111204f

using bf16x8 = __attribute__((ext_vector_type(8))) short;   // 8 bf16 = 4 VGPR
using f32x16 = __attribute__((ext_vector_type(16))) float;  // 32x32 MFMA acc

__device__ __forceinline__ float exp2f_fast(float x) { return __builtin_amdgcn_exp2f(x); }
__device__ __forceinline__ f32x16 mfma32(bf16x8 a, bf16x8 b, f32x16 c) {
  return __builtin_amdgcn_mfma_f32_32x32x16_bf16(a, b, c, 0, 0, 0);
}
// round-to-nearest-even fp32 -> bf16 bits
__device__ __forceinline__ unsigned f2bfbits(float f) {
  unsigned u = __builtin_bit_cast(unsigned, f);
  return (u + 0x7fffu + ((u >> 16) & 1u)) >> 16;
}
__device__ __forceinline__ float bfval(unsigned hb) {
  return __builtin_bit_cast(float, hb << 16);
}
__device__ __forceinline__ unsigned pkb(float a, float b) {
  return f2bfbits(a) | (f2bfbits(b) << 16);
}
// async global->LDS DMA, 16B/lane; LDS dest = wave-uniform base + lane*16
__device__ __forceinline__ void gl2lds16(const void* g, void* l) {
  __builtin_amdgcn_global_load_lds(
      (const __attribute__((address_space(1))) unsigned*)g,
      (__attribute__((address_space(3))) unsigned*)l, 16, 0, 0);
}
// swizzled LDS frag read: 16B slot s of row r lives at phys slot s^(r&7)
__device__ __forceinline__ bf16x8 lds_frag(const unsigned short* base, int row, int slot) {
  int phys = slot ^ (row & 7);
  return *(const bf16x8*)&base[row * 64 + phys * 8];
}

// ---------------- W -> W^T bf16 hi/lo (tiny) ----------------
// wT layout: [mat][c (0..63)][d (0..255)]
__global__ __launch_bounds__(256) void wconv_kernel(
    const float* __restrict__ wq, const float* __restrict__ wk, const float* __restrict__ wv,
    unsigned short* __restrict__ wThi, unsigned short* __restrict__ wTlo)
{
  int flat = blockIdx.x * 256 + threadIdx.x;   // 0..8191
  const float* Ws[3] = {wq, wk, wv};
  #pragma unroll
  for (int j = 0; j < 6; ++j) {
    int idx = flat + j * 8192;                 // 0..49151
    int m = idx >> 14, rem = idx & 16383;
    int c = rem >> 8, d = rem & 255;
    float val = Ws[m][d * 64 + c];
    unsigned hb = f2bfbits(val);
    wThi[idx] = (unsigned short)hb;
    wTlo[idx] = (unsigned short)f2bfbits(val - bfval(hb));
  }
}

// ---------------- QKV projection via MFMA (bf16x3) ----------------
// grid (128, 3), block 128 (2 waves). Wave: 32 x-rows x 64 cols of one matrix.
// q,k stored row-major hi/lo bf16 (q pre-scaled); v stored TRANSPOSED hi/lo.
__global__ __launch_bounds__(128) void qkv_mfma_kernel(
    const float* __restrict__ x,
    const unsigned short* __restrict__ wThi, const unsigned short* __restrict__ wTlo,
    unsigned short* __restrict__ qhi, unsigned short* __restrict__ qlo,
    unsigned short* __restrict__ khi, unsigned short* __restrict__ klo,
    unsigned short* __restrict__ vThi, unsigned short* __restrict__ vTlo)
{
  const int tid = threadIdx.x, lane = tid & 63, w = tid >> 6;
  const int qr = lane & 31, h = lane >> 5;
  const int mat = blockIdx.y;
  const int r0 = blockIdx.x * 64 + w * 32;

  const unsigned short* wh = &wThi[mat << 14];
  const unsigned short* wl = &wTlo[mat << 14];

  f32x16 acc0, acc1;
  #pragma unroll
  for (int i = 0; i < 16; ++i) { acc0[i] = 0.f; acc1[i] = 0.f; }

  #pragma unroll
  for (int kc = 0; kc < 16; ++kc) {
    // x frag (row r0+qr, d = kc*16+8h..+7), converted fp32 -> bf16 hi/lo
    const float* xp = &x[(size_t)(r0 + qr) * DIN + kc * 16 + 8 * h];
    float4 xa = *(const float4*)xp;
    float4 xb = *(const float4*)(xp + 4);
    union { unsigned short u[8]; bf16x8 v; } ah, al;
    float xs[8] = {xa.x, xa.y, xa.z, xa.w, xb.x, xb.y, xb.z, xb.w};
    #pragma unroll
    for (int j = 0; j < 8; ++j) {
      unsigned hb = f2bfbits(xs[j]);
      ah.u[j] = (unsigned short)hb;
      al.u[j] = (unsigned short)f2bfbits(xs[j] - bfval(hb));
    }
    // W^T frags, ct = 0,1
    bf16x8 bh0 = *(const bf16x8*)&wh[(size_t)(qr)      * DIN + kc * 16 + 8 * h];
    bf16x8 bh1 = *(const bf16x8*)&wh[(size_t)(32 + qr) * DIN + kc * 16 + 8 * h];
    bf16x8 bl0 = *(const bf16x8*)&wl[(size_t)(qr)      * DIN + kc * 16 + 8 * h];
    bf16x8 bl1 = *(const bf16x8*)&wl[(size_t)(32 + qr) * DIN + kc * 16 + 8 * h];
    if (mat < 2) {       // D[r(reg)][c(lane)] = x . W
      acc0 = mfma32(ah.v, bh0, acc0);
      acc0 = mfma32(al.v, bh0, acc0);
      acc0 = mfma32(ah.v, bl0, acc0);
      acc1 = mfma32(ah.v, bh1, acc1);
      acc1 = mfma32(al.v, bh1, acc1);
      acc1 = mfma32(ah.v, bl1, acc1);
    } else {             // D[c(reg)][r(lane)] = (x . Wv)^T
      acc0 = mfma32(bh0, ah.v, acc0);
      acc0 = mfma32(bl0, ah.v, acc0);
      acc0 = mfma32(bh0, al.v, acc0);
      acc1 = mfma32(bh1, ah.v, acc1);
      acc1 = mfma32(bl1, ah.v, acc1);
      acc1 = mfma32(bh1, al.v, acc1);
    }
  }

  if (mat < 2) {
    unsigned short* oh = mat ? khi : qhi;
    unsigned short* ol = mat ? klo : qlo;
    const float scale = (mat == 0) ? QSCALE : 1.0f;
    #pragma unroll
    for (int ct = 0; ct < 2; ++ct) {
      const f32x16& A = ct ? acc1 : acc0;
      #pragma unroll
      for (int i = 0; i < 16; ++i) {
        int r = r0 + (i & 3) + 8 * (i >> 2) + 4 * h;
        int c = ct * 32 + qr;
        float val = A[i] * scale;
        unsigned hb = f2bfbits(val);
        oh[(size_t)r * DOUT + c] = (unsigned short)hb;
        ol[(size_t)r * DOUT + c] = (unsigned short)f2bfbits(val - bfval(hb));
      }
    }
  } else {
    #pragma unroll
    for (int ct = 0; ct < 2; ++ct) {
      const f32x16& A = ct ? acc1 : acc0;
      #pragma unroll
      for (int i = 0; i < 16; ++i) {
        int c = ct * 32 + (i & 3) + 8 * (i >> 2) + 4 * h;
        int r = r0 + qr;
        float val = A[i];
        unsigned hb = f2bfbits(val);
        vThi[(size_t)c * SEQ + r] = (unsigned short)hb;
        vTlo[(size_t)c * SEQ + r] = (unsigned short)f2bfbits(val - bfval(hb));
      }
    }
  }
}

// ---------------- MFMA flash attention, split-K ----------------
// 4 waves x 64 q-rows = 256 q-rows/block. KVBLK=64 double-buffered, staged by
// global_load_lds with source-side swizzle. Each K/V frag read feeds 2 q-tiles.
__global__ __launch_bounds__(256, 2) void attn_mfma_kernel(
    const unsigned short* __restrict__ qhi, const unsigned short* __restrict__ qlo,
    const unsigned short* __restrict__ khi, const unsigned short* __restrict__ klo,
    const unsigned short* __restrict__ vThi, const unsigned short* __restrict__ vTlo,
    float* __restrict__ opart, float2* __restrict__ mlpart, int slice_len)
{
  __shared__ __align__(1024) unsigned short smx[2][4][4096];  // 64 KB
  const int tid  = threadIdx.x;
  const int lane = tid & 63;
  const int w    = tid >> 6;          // wave 0..3
  const int qr   = lane & 31;
  const int h    = lane >> 5;
  const int split = blockIdx.y;
  const int j0   = split * slice_len;
  const int NT   = slice_len >> 6;
  const int qg0  = blockIdx.x * 256 + w * 64 + qr;
  const int qg1  = qg0 + 32;

  // resident q_hi frags (q_lo streamed from L2 in the loop)
  bf16x8 qh0[4], qh1[4];
  #pragma unroll
  for (int c = 0; c < 4; ++c) {
    qh0[c] = *(const bf16x8*)&qhi[(size_t)qg0 * DOUT + c * 16 + 8 * h];
    qh1[c] = *(const bf16x8*)&qhi[(size_t)qg1 * DOUT + c * 16 + 8 * h];
  }

  f32x16 o00, o01, o10, o11;   // o[qt][dt]
  #pragma unroll
  for (int i = 0; i < 16; ++i) { o00[i] = 0.f; o01[i] = 0.f; o10[i] = 0.f; o11[i] = 0.f; }
  float m0 = -1.0e30f, m1 = -1.0e30f, l0 = 0.f, l1 = 0.f;

  // staging: wave w DMAs array w. Lane's 16B lands at row 8i+(lane>>3),
  // phys slot lane&7 -> fetch logical slot (lane&7)^(lane>>3) from global.
  const int srow_l = lane >> 3;
  const int sslot  = (lane & 7) ^ srow_l;

  auto stage = [&](int t, int nb) {
    const int r0k = j0 + t * 64;
    if (w < 2) {
      const unsigned short* g = (w == 0) ? khi : klo;
      #pragma unroll
      for (int i = 0; i < 8; ++i) {
        int row = 8 * i + srow_l;
        gl2lds16(&g[(size_t)(r0k + row) * DOUT + sslot * 8], &smx[nb][w][i * 512]);
      }
    } else {
      const unsigned short* g = (w == 2) ? vThi : vTlo;
      #pragma unroll
      for (int i = 0; i < 8; ++i) {
        int row = 8 * i + srow_l;
        gl2lds16(&g[(size_t)row * SEQ + r0k + sslot * 8], &smx[nb][w][i * 512]);
      }
    }
  };

  stage(0, 0);
  __syncthreads();      // drains vmcnt (DMA) + barrier

  for (int t = 0; t < NT; ++t) {
    const int b = t & 1;
    if (t + 1 < NT) stage(t + 1, b ^ 1);

    const unsigned short* KH = &smx[b][0][0];
    const unsigned short* KL = &smx[b][1][0];
    const unsigned short* VH = &smx[b][2][0];
    const unsigned short* VL = &smx[b][3][0];

    // ---- S^T = K.Q^T (bf16x3), shared K-frags across both q-tiles
    f32x16 s00, s01, s10, s11;    // s[qt][ktile]
    #pragma unroll
    for (int i = 0; i < 16; ++i) { s00[i] = 0.f; s01[i] = 0.f; s10[i] = 0.f; s11[i] = 0.f; }
    #pragma unroll
    for (int c = 0; c < 4; ++c) {
      bf16x8 kh0 = lds_frag(KH, qr,      2 * c + h);
      bf16x8 kh1 = lds_frag(KH, qr + 32, 2 * c + h);
      bf16x8 kl0 = lds_frag(KL, qr,      2 * c + h);
      bf16x8 kl1 = lds_frag(KL, qr + 32, 2 * c + h);
      bf16x8 ql0 = *(const bf16x8*)&qlo[(size_t)qg0 * DOUT + c * 16 + 8 * h];
      bf16x8 ql1 = *(const bf16x8*)&qlo[(size_t)qg1 * DOUT + c * 16 + 8 * h];
      s00 = mfma32(kh0, qh0[c], s00);  s01 = mfma32(kh1, qh0[c], s01);
      s10 = mfma32(kh0, qh1[c], s10);  s11 = mfma32(kh1, qh1[c], s11);
      s00 = mfma32(kl0, qh0[c], s00);  s01 = mfma32(kl1, qh0[c], s01);
      s10 = mfma32(kl0, qh1[c], s10);  s11 = mfma32(kl1, qh1[c], s11);
      s00 = mfma32(kh0, ql0, s00);     s01 = mfma32(kh1, ql0, s01);
      s10 = mfma32(kh0, ql1, s10);     s11 = mfma32(kh1, ql1, s11);
    }

    // ---- online softmax (exp2 domain, deferred max) + pack P^T bf16 frags
    unsigned fw0[4][4], fw1[4][4];
    auto softmax_pack = [&](f32x16& sA, f32x16& sB, f32x16& oA, f32x16& oB,
                            float& mm, float& ll, unsigned fw[4][4]) {
      float pm = sA[0];
      #pragma unroll
      for (int i = 1; i < 16; ++i) pm = fmaxf(pm, sA[i]);
      #pragma unroll
      for (int i = 0; i < 16; ++i) pm = fmaxf(pm, sB[i]);
      pm = fmaxf(pm, __shfl_xor(pm, 32));
      if (__any(pm > mm + 40.0f)) {
        float nm = fmaxf(mm, pm);
        float r = exp2f_fast(mm - nm);
        #pragma unroll
        for (int i = 0; i < 16; ++i) { oA[i] *= r; oB[i] *= r; }
        ll *= r; mm = nm;
      }
      #pragma unroll
      for (int i = 0; i < 16; ++i) sA[i] = exp2f_fast(sA[i] - mm);
      #pragma unroll
      for (int i = 0; i < 16; ++i) sB[i] = exp2f_fast(sB[i] - mm);
      float ls = 0.f;
      #pragma unroll
      for (int i = 0; i < 16; ++i) ls += sA[i] + sB[i];
      ll += ls + __shfl_xor(ls, 32);
      #pragma unroll
      for (int ti = 0; ti < 2; ++ti) {
        #pragma unroll
        for (int c = 0; c < 2; ++c) {
          const f32x16& S = ti ? sB : sA;
          unsigned X0 = pkb(S[8*c+0], S[8*c+1]);
          unsigned Y0 = pkb(S[8*c+2], S[8*c+3]);
          unsigned X1 = pkb(S[8*c+4], S[8*c+5]);
          unsigned Y1 = pkb(S[8*c+6], S[8*c+7]);
          unsigned rX0 = __shfl_xor(X0, 32);
          unsigned rY0 = __shfl_xor(Y0, 32);
          unsigned rX1 = __shfl_xor(X1, 32);
          unsigned rY1 = __shfl_xor(Y1, 32);
          fw[ti*2+c][0] = h ? rX1 : X0;
          fw[ti*2+c][1] = h ? rY1 : Y0;
          fw[ti*2+c][2] = h ? X1  : rX0;
          fw[ti*2+c][3] = h ? Y1  : rY0;
        }
      }
    };
    softmax_pack(s00, s01, o00, o01, m0, l0, fw0);
    softmax_pack(s10, s11, o10, o11, m1, l1, fw1);

    // ---- O^T += V^T.P^T (V bf16x2), shared V-frags across both q-tiles
    #pragma unroll
    for (int dt = 0; dt < 2; ++dt) {
      f32x16& O0 = dt ? o01 : o00;
      f32x16& O1 = dt ? o11 : o10;
      #pragma unroll
      for (int kc = 0; kc < 4; ++kc) {
        bf16x8 vh = lds_frag(VH, qr + 32 * dt, 2 * kc + h);
        bf16x8 vl = lds_frag(VL, qr + 32 * dt, 2 * kc + h);
        uint4 u0 = {fw0[kc][0], fw0[kc][1], fw0[kc][2], fw0[kc][3]};
        uint4 u1 = {fw1[kc][0], fw1[kc][1], fw1[kc][2], fw1[kc][3]};
        bf16x8 p0 = __builtin_bit_cast(bf16x8, u0);
        bf16x8 p1 = __builtin_bit_cast(bf16x8, u1);
        O0 = mfma32(vh, p0, O0);
        O0 = mfma32(vl, p0, O0);
        O1 = mfma32(vh, p1, O1);
        O1 = mfma32(vl, p1, O1);
      }
    }

    __syncthreads();   // drains this iter's DMA (vmcnt) + protects both buffers
  }

  // ---- epilogue: d = (i&3) + 8*(i>>2) + 4h (+32 for dt=1)
  const size_t ob0 = ((size_t)split * SEQ + qg0) * DOUT;
  const size_t ob1 = ((size_t)split * SEQ + qg1) * DOUT;
  #pragma unroll
  for (int b2 = 0; b2 < 4; ++b2) {
    int d0 = 8 * b2 + 4 * h;
    float4 v00 = {o00[4*b2+0], o00[4*b2+1], o00[4*b2+2], o00[4*b2+3]};
    float4 v01 = {o01[4*b2+0], o01[4*b2+1], o01[4*b2+2], o01[4*b2+3]};
    float4 v10 = {o10[4*b2+0], o10[4*b2+1], o10[4*b2+2], o10[4*b2+3]};
    float4 v11 = {o11[4*b2+0], o11[4*b2+1], o11[4*b2+2], o11[4*b2+3]};
    *(float4*)&opart[ob0 + d0]      = v00;
    *(float4*)&opart[ob0 + 32 + d0] = v01;
    *(float4*)&opart[ob1 + d0]      = v10;
    *(float4*)&opart[ob1 + 32 + d0] = v11;
  }
  if (h == 0) {
    mlpart[(size_t)split * SEQ + qg0] = make_float2(m0, l0);
    mlpart[(size_t)split * SEQ + qg1] = make_float2(m1, l1);
  }
}

// ---------------- combine split-K partials ----------------
__global__ __launch_bounds__(256) void combine_kernel(
    const float* __restrict__ opart, const float2* __restrict__ mlpart,
    float* __restrict__ out, int S)
{
  const int tid = threadIdx.x;
  const int row = blockIdx.x * 16 + (tid >> 4);
  const int c4  = tid & 15;
  float mstar = -3.0e38f;
  for (int i = 0; i < S; ++i)
    mstar = fmaxf(mstar, mlpart[(size_t)i * SEQ + row].x);
  float L = 0.f, ax = 0.f, ay = 0.f, az = 0.f, aw = 0.f;
  for (int i = 0; i < S; ++i) {
    float2 ml = mlpart[(size_t)i * SEQ + row];
    float  wgt = exp2f_fast(ml.x - mstar);
    L = fmaf(wgt, ml.y, L);
    float4 ov = ((const float4*)(opart + ((size_t)i * SEQ + row) * DOUT))[c4];
    ax = fmaf(wgt, ov.x, ax); ay = fmaf(wgt, ov.y, ay);
    az = fmaf(wgt, ov.z, az); aw = fmaf(wgt, ov.w, aw);
  }
  float inv = 1.0f / L;
  float4 res = {ax * inv, ay * inv, az * inv, aw * inv};
  ((float4*)(out + (size_t)row * DOUT))[c4] = res;
}

extern "C" void kernel_launch(void* const* d_in, const int* in_sizes, int n_in,
                              void* d_out, int out_size, void* d_ws, size_t ws_size,
                              hipStream_t stream)
{
  const float* x  = (const float*)d_in[0];
  const float* wq = (const float*)d_in[1];
  const float* wk = (const float*)d_in[2];
  const float* wv = (const float*)d_in[3];
  float* out = (float*)d_out;

  char* ws = (char*)d_ws;
  const size_t MB = (size_t)SEQ * DOUT * 2;   // 1 MB per bf16 [SEQ][64] array
  unsigned short* qhi  = (unsigned short*)(ws);
  unsigned short* qlo  = (unsigned short*)(ws + MB);
  unsigned short* khi  = (unsigned short*)(ws + 2 * MB);
  unsigned short* klo  = (unsigned short*)(ws + 3 * MB);
  unsigned short* vThi = (unsigned short*)(ws + 4 * MB);
  unsigned short* vTlo = (unsigned short*)(ws + 5 * MB);
  unsigned short* wThi = (unsigned short*)(ws + 6 * MB);            // 96 KB
  unsigned short* wTlo = (unsigned short*)(ws + 6 * MB + 131072);   // 96 KB
  float* opart = (float*)(ws + 7 * MB);

  int S = 16;
  while (S > 1) {
    size_t need = 7 * MB + ((size_t)S * SEQ * DOUT + (size_t)S * SEQ * 2) * 4;
    if (need <= ws_size) break;
    S >>= 1;
  }
  float2* mlpart = (float2*)(opart + (size_t)S * SEQ * DOUT);
  const int slice_len = SEQ / S;

  wconv_kernel<<<32, 256, 0, stream>>>(wq, wk, wv, wThi, wTlo);
  qkv_mfma_kernel<<<dim3(SEQ / 64, 3), 128, 0, stream>>>(
      x, wThi, wTlo, qhi, qlo, khi, klo, vThi, vTlo);
  attn_mfma_kernel<<<dim3(SEQ / 256, S), 256, 0, stream>>>(
      qhi, qlo, khi, klo, vThi, vTlo, opart, mlpart, slice_len);
  combine_kernel<<<SEQ / 16, 256, 0, stream>>>(opart, mlpart, out, S);
}

// Round 11
// 130.649 us; speedup vs baseline: 3.3409x; 1.0133x over previous
//
#include <hip/hip_runtime.h>
#include <hip/hip_bf16.h>

#define SEQ   8192
#define DIN   256
#define DOUT  64
// log2(e)/sqrt(DOUT) folded into q -> softmax in exp2 domain
#define QSCALE 0.1803368801111204f

using bf16x8 = __attribute__((ext_vector_type(8))) short;   // 8 bf16 = 4 VGPR
using f32x16 = __attribute__((ext_vector_type(16))) float;  // 32x32 MFMA acc

__device__ __forceinline__ float exp2f_fast(float x) { return __builtin_amdgcn_exp2f(x); }
__device__ __forceinline__ f32x16 mfma32(bf16x8 a, bf16x8 b, f32x16 c) {
  return __builtin_amdgcn_mfma_f32_32x32x16_bf16(a, b, c, 0, 0, 0);
}
// packed fp32x2 -> bf16x2 (RNE), single VALU op (T12; no builtin on gfx950)
__device__ __forceinline__ unsigned cvtpk(float lo, float hi) {
  unsigned r;
  asm("v_cvt_pk_bf16_f32 %0, %1, %2" : "=v"(r) : "v"(lo), "v"(hi));
  return r;
}
// round-to-nearest-even fp32 -> bf16 bits (scalar fallback, epilogue-only)
__device__ __forceinline__ unsigned f2bfbits(float f) {
  unsigned u = __builtin_bit_cast(unsigned, f);
  return (u + 0x7fffu + ((u >> 16) & 1u)) >> 16;
}
__device__ __forceinline__ float bfval(unsigned hb) {
  return __builtin_bit_cast(float, hb << 16);
}
// fp32 pair -> (hi bf16x2, lo bf16x2): 2 cvt_pk + 2 sub + 2 bit-ops
__device__ __forceinline__ void split2(float a, float b, unsigned& hi, unsigned& lo) {
  hi = cvtpk(a, b);
  float ha = __builtin_bit_cast(float, hi << 16);
  float hb = __builtin_bit_cast(float, hi & 0xffff0000u);
  lo = cvtpk(a - ha, b - hb);
}
// async global->LDS DMA, 16B/lane; LDS dest = wave-uniform base + lane*16
__device__ __forceinline__ void gl2lds16(const void* g, void* l) {
  __builtin_amdgcn_global_load_lds(
      (const __attribute__((address_space(1))) unsigned*)g,
      (__attribute__((address_space(3))) unsigned*)l, 16, 0, 0);
}
// swizzled LDS frag read: 16B slot s of row r lives at phys slot s^(r&7)
__device__ __forceinline__ bf16x8 lds_frag(const unsigned short* base, int row, int slot) {
  int phys = slot ^ (row & 7);
  return *(const bf16x8*)&base[row * 64 + phys * 8];
}

// ---------------- W -> W^T bf16 hi/lo (tiny) ----------------
// wT layout: [mat][c (0..63)][d (0..255)]
__global__ __launch_bounds__(256) void wconv_kernel(
    const float* __restrict__ wq, const float* __restrict__ wk, const float* __restrict__ wv,
    unsigned short* __restrict__ wThi, unsigned short* __restrict__ wTlo)
{
  int flat = blockIdx.x * 256 + threadIdx.x;   // 0..8191
  const float* Ws[3] = {wq, wk, wv};
  #pragma unroll
  for (int j = 0; j < 6; ++j) {
    int idx = flat + j * 8192;                 // 0..49151
    int m = idx >> 14, rem = idx & 16383;
    int c = rem >> 8, d = rem & 255;
    float val = Ws[m][d * 64 + c];
    unsigned hb = f2bfbits(val);
    wThi[idx] = (unsigned short)hb;
    wTlo[idx] = (unsigned short)f2bfbits(val - bfval(hb));
  }
}

// ---------------- QKV projection via MFMA (bf16x3) ----------------
// grid (256, 3), block 128 (2 waves). Wave: 32 x-rows x 32 cols (ct = wave id).
// q,k stored row-major hi/lo bf16 (q pre-scaled); v stored TRANSPOSED hi/lo.
__global__ __launch_bounds__(128) void qkv_mfma_kernel(
    const float* __restrict__ x,
    const unsigned short* __restrict__ wThi, const unsigned short* __restrict__ wTlo,
    unsigned short* __restrict__ qhi, unsigned short* __restrict__ qlo,
    unsigned short* __restrict__ khi, unsigned short* __restrict__ klo,
    unsigned short* __restrict__ vThi, unsigned short* __restrict__ vTlo)
{
  const int tid = threadIdx.x, lane = tid & 63, ct = tid >> 6;
  const int qr = lane & 31, h = lane >> 5;
  const int mat = blockIdx.y;
  const int r0 = blockIdx.x * 32;

  const unsigned short* wh = &wThi[(mat << 14) + (size_t)(ct * 32) * DIN];
  const unsigned short* wl = &wTlo[(mat << 14) + (size_t)(ct * 32) * DIN];
  const float* xrow = &x[(size_t)(r0 + qr) * DIN + 8 * h];

  f32x16 acc;
  #pragma unroll
  for (int i = 0; i < 16; ++i) acc[i] = 0.f;

  float4 xa = *(const float4*)&xrow[0];
  float4 xb = *(const float4*)&xrow[4];
  #pragma unroll
  for (int kc = 0; kc < 16; ++kc) {
    float4 na, nb;
    if (kc < 15) {
      na = *(const float4*)&xrow[(kc + 1) * 16];
      nb = *(const float4*)&xrow[(kc + 1) * 16 + 4];
    }
    uint4 hu, lu;
    split2(xa.x, xa.y, hu.x, lu.x);
    split2(xa.z, xa.w, hu.y, lu.y);
    split2(xb.x, xb.y, hu.z, lu.z);
    split2(xb.z, xb.w, hu.w, lu.w);
    bf16x8 ah = __builtin_bit_cast(bf16x8, hu);
    bf16x8 al = __builtin_bit_cast(bf16x8, lu);
    bf16x8 bh = *(const bf16x8*)&wh[(size_t)qr * DIN + kc * 16 + 8 * h];
    bf16x8 bl = *(const bf16x8*)&wl[(size_t)qr * DIN + kc * 16 + 8 * h];
    if (mat < 2) {       // D[r(reg)][c(lane)] = x . W
      acc = mfma32(ah, bh, acc);
      acc = mfma32(al, bh, acc);
      acc = mfma32(ah, bl, acc);
    } else {             // D[c(reg)][r(lane)] = (x . Wv)^T
      acc = mfma32(bh, ah, acc);
      acc = mfma32(bl, ah, acc);
      acc = mfma32(bh, al, acc);
    }
    xa = na; xb = nb;
  }

  if (mat < 2) {
    unsigned short* oh = mat ? khi : qhi;
    unsigned short* ol = mat ? klo : qlo;
    const float scale = (mat == 0) ? QSCALE : 1.0f;
    const int c = ct * 32 + qr;
    #pragma unroll
    for (int i = 0; i < 16; i += 2) {
      float v0 = acc[i] * scale, v1 = acc[i + 1] * scale;
      unsigned hp, lp;
      split2(v0, v1, hp, lp);
      int r = r0 + (i & 3) + 8 * (i >> 2) + 4 * h;   // i even: rows r, r+1
      oh[(size_t)r * DOUT + c]       = (unsigned short)hp;
      oh[(size_t)(r + 1) * DOUT + c] = (unsigned short)(hp >> 16);
      ol[(size_t)r * DOUT + c]       = (unsigned short)lp;
      ol[(size_t)(r + 1) * DOUT + c] = (unsigned short)(lp >> 16);
    }
  } else {
    const int r = r0 + qr;
    #pragma unroll
    for (int i = 0; i < 16; i += 2) {
      unsigned hp, lp;
      split2(acc[i], acc[i + 1], hp, lp);
      int c = ct * 32 + (i & 3) + 8 * (i >> 2) + 4 * h;
      vThi[(size_t)c * SEQ + r]       = (unsigned short)hp;
      vThi[(size_t)(c + 1) * SEQ + r] = (unsigned short)(hp >> 16);
      vTlo[(size_t)c * SEQ + r]       = (unsigned short)lp;
      vTlo[(size_t)(c + 1) * SEQ + r] = (unsigned short)(lp >> 16);
    }
  }
}

// ---------------- MFMA flash attention, split-K ----------------
// 4 waves x 64 q-rows = 256 q-rows/block. KVBLK=64 double-buffered, staged by
// global_load_lds with source-side swizzle. Each K/V frag read feeds 2 q-tiles.
__global__ __launch_bounds__(256, 2) void attn_mfma_kernel(
    const unsigned short* __restrict__ qhi, const unsigned short* __restrict__ qlo,
    const unsigned short* __restrict__ khi, const unsigned short* __restrict__ klo,
    const unsigned short* __restrict__ vThi, const unsigned short* __restrict__ vTlo,
    float* __restrict__ opart, float2* __restrict__ mlpart, int slice_len)
{
  __shared__ __align__(1024) unsigned short smx[2][4][4096];  // 64 KB
  const int tid  = threadIdx.x;
  const int lane = tid & 63;
  const int w    = tid >> 6;          // wave 0..3
  const int qr   = lane & 31;
  const int h    = lane >> 5;
  const int split = blockIdx.y;
  const int j0   = split * slice_len;
  const int NT   = slice_len >> 6;
  const int qg0  = blockIdx.x * 256 + w * 64 + qr;
  const int qg1  = qg0 + 32;

  // resident q frags: hi AND lo hoisted (loop-invariant across all NT iters)
  bf16x8 qh0[4], qh1[4], qlr0[4], qlr1[4];
  #pragma unroll
  for (int c = 0; c < 4; ++c) {
    qh0[c]  = *(const bf16x8*)&qhi[(size_t)qg0 * DOUT + c * 16 + 8 * h];
    qh1[c]  = *(const bf16x8*)&qhi[(size_t)qg1 * DOUT + c * 16 + 8 * h];
    qlr0[c] = *(const bf16x8*)&qlo[(size_t)qg0 * DOUT + c * 16 + 8 * h];
    qlr1[c] = *(const bf16x8*)&qlo[(size_t)qg1 * DOUT + c * 16 + 8 * h];
  }

  f32x16 o00, o01, o10, o11;   // o[qt][dt]
  #pragma unroll
  for (int i = 0; i < 16; ++i) { o00[i] = 0.f; o01[i] = 0.f; o10[i] = 0.f; o11[i] = 0.f; }
  float m0 = -1.0e30f, m1 = -1.0e30f, l0 = 0.f, l1 = 0.f;

  // staging: wave w DMAs array w. Lane's 16B lands at row 8i+(lane>>3),
  // phys slot lane&7 -> fetch logical slot (lane&7)^(lane>>3) from global.
  const int srow_l = lane >> 3;
  const int sslot  = (lane & 7) ^ srow_l;

  auto stage = [&](int t, int nb) {
    const int r0k = j0 + t * 64;
    if (w < 2) {
      const unsigned short* g = (w == 0) ? khi : klo;
      #pragma unroll
      for (int i = 0; i < 8; ++i) {
        int row = 8 * i + srow_l;
        gl2lds16(&g[(size_t)(r0k + row) * DOUT + sslot * 8], &smx[nb][w][i * 512]);
      }
    } else {
      const unsigned short* g = (w == 2) ? vThi : vTlo;
      #pragma unroll
      for (int i = 0; i < 8; ++i) {
        int row = 8 * i + srow_l;
        gl2lds16(&g[(size_t)row * SEQ + r0k + sslot * 8], &smx[nb][w][i * 512]);
      }
    }
  };

  stage(0, 0);
  __syncthreads();      // drains vmcnt (DMA) + barrier

  for (int t = 0; t < NT; ++t) {
    const int b = t & 1;
    if (t + 1 < NT) stage(t + 1, b ^ 1);

    const unsigned short* KH = &smx[b][0][0];
    const unsigned short* KL = &smx[b][1][0];
    const unsigned short* VH = &smx[b][2][0];
    const unsigned short* VL = &smx[b][3][0];

    // ---- S^T = K.Q^T (bf16x3), shared K-frags across both q-tiles
    f32x16 s00, s01, s10, s11;    // s[qt][ktile]
    #pragma unroll
    for (int i = 0; i < 16; ++i) { s00[i] = 0.f; s01[i] = 0.f; s10[i] = 0.f; s11[i] = 0.f; }
    __builtin_amdgcn_s_setprio(1);
    #pragma unroll
    for (int c = 0; c < 4; ++c) {
      bf16x8 kh0 = lds_frag(KH, qr,      2 * c + h);
      bf16x8 kh1 = lds_frag(KH, qr + 32, 2 * c + h);
      bf16x8 kl0 = lds_frag(KL, qr,      2 * c + h);
      bf16x8 kl1 = lds_frag(KL, qr + 32, 2 * c + h);
      s00 = mfma32(kh0, qh0[c], s00);  s01 = mfma32(kh1, qh0[c], s01);
      s10 = mfma32(kh0, qh1[c], s10);  s11 = mfma32(kh1, qh1[c], s11);
      s00 = mfma32(kl0, qh0[c], s00);  s01 = mfma32(kl1, qh0[c], s01);
      s10 = mfma32(kl0, qh1[c], s10);  s11 = mfma32(kl1, qh1[c], s11);
      s00 = mfma32(kh0, qlr0[c], s00); s01 = mfma32(kh1, qlr0[c], s01);
      s10 = mfma32(kh0, qlr1[c], s10); s11 = mfma32(kh1, qlr1[c], s11);
    }
    __builtin_amdgcn_s_setprio(0);

    // ---- online softmax (exp2 domain, deferred max) + pack P^T bf16 frags
    unsigned fw0[4][4], fw1[4][4];
    auto softmax_pack = [&](f32x16& sA, f32x16& sB, f32x16& oA, f32x16& oB,
                            float& mm, float& ll, unsigned fw[4][4]) {
      // max reduce shaped for v_max3 fusion
      float pm = fmaxf(sA[0], sA[1]);
      #pragma unroll
      for (int i = 2; i < 16; i += 2) pm = fmaxf(pm, fmaxf(sA[i], sA[i + 1]));
      #pragma unroll
      for (int i = 0; i < 16; i += 2) pm = fmaxf(pm, fmaxf(sB[i], sB[i + 1]));
      pm = fmaxf(pm, __shfl_xor(pm, 32));
      if (__any(pm > mm + 40.0f)) {
        float nm = fmaxf(mm, pm);
        float r = exp2f_fast(mm - nm);
        #pragma unroll
        for (int i = 0; i < 16; ++i) { oA[i] *= r; oB[i] *= r; }
        ll *= r; mm = nm;
      }
      #pragma unroll
      for (int i = 0; i < 16; ++i) sA[i] = exp2f_fast(sA[i] - mm);
      #pragma unroll
      for (int i = 0; i < 16; ++i) sB[i] = exp2f_fast(sB[i] - mm);
      float ls = 0.f;
      #pragma unroll
      for (int i = 0; i < 16; ++i) ls += sA[i] + sB[i];
      ll += ls + __shfl_xor(ls, 32);
      // pack P^T to bf16 frags via v_cvt_pk (1 inst/pair) + half-swap shfls
      #pragma unroll
      for (int ti = 0; ti < 2; ++ti) {
        #pragma unroll
        for (int c = 0; c < 2; ++c) {
          const f32x16& S = ti ? sB : sA;
          unsigned X0 = cvtpk(S[8*c+0], S[8*c+1]);
          unsigned Y0 = cvtpk(S[8*c+2], S[8*c+3]);
          unsigned X1 = cvtpk(S[8*c+4], S[8*c+5]);
          unsigned Y1 = cvtpk(S[8*c+6], S[8*c+7]);
          unsigned rX0 = __shfl_xor(X0, 32);
          unsigned rY0 = __shfl_xor(Y0, 32);
          unsigned rX1 = __shfl_xor(X1, 32);
          unsigned rY1 = __shfl_xor(Y1, 32);
          fw[ti*2+c][0] = h ? rX1 : X0;
          fw[ti*2+c][1] = h ? rY1 : Y0;
          fw[ti*2+c][2] = h ? X1  : rX0;
          fw[ti*2+c][3] = h ? Y1  : rY0;
        }
      }
    };
    softmax_pack(s00, s01, o00, o01, m0, l0, fw0);
    softmax_pack(s10, s11, o10, o11, m1, l1, fw1);

    // ---- O^T += V^T.P^T (V bf16x2), shared V-frags across both q-tiles
    __builtin_amdgcn_s_setprio(1);
    #pragma unroll
    for (int dt = 0; dt < 2; ++dt) {
      f32x16& O0 = dt ? o01 : o00;
      f32x16& O1 = dt ? o11 : o10;
      #pragma unroll
      for (int kc = 0; kc < 4; ++kc) {
        bf16x8 vh = lds_frag(VH, qr + 32 * dt, 2 * kc + h);
        bf16x8 vl = lds_frag(VL, qr + 32 * dt, 2 * kc + h);
        uint4 u0 = {fw0[kc][0], fw0[kc][1], fw0[kc][2], fw0[kc][3]};
        uint4 u1 = {fw1[kc][0], fw1[kc][1], fw1[kc][2], fw1[kc][3]};
        bf16x8 p0 = __builtin_bit_cast(bf16x8, u0);
        bf16x8 p1 = __builtin_bit_cast(bf16x8, u1);
        O0 = mfma32(vh, p0, O0);
        O0 = mfma32(vl, p0, O0);
        O1 = mfma32(vh, p1, O1);
        O1 = mfma32(vl, p1, O1);
      }
    }
    __builtin_amdgcn_s_setprio(0);

    __syncthreads();   // drains this iter's DMA (vmcnt) + protects both buffers
  }

  // ---- epilogue: d = (i&3) + 8*(i>>2) + 4h (+32 for dt=1)
  const size_t ob0 = ((size_t)split * SEQ + qg0) * DOUT;
  const size_t ob1 = ((size_t)split * SEQ + qg1) * DOUT;
  #pragma unroll
  for (int b2 = 0; b2 < 4; ++b2) {
    int d0 = 8 * b2 + 4 * h;
    float4 v00 = {o00[4*b2+0], o00[4*b2+1], o00[4*b2+2], o00[4*b2+3]};
    float4 v01 = {o01[4*b2+0], o01[4*b2+1], o01[4*b2+2], o01[4*b2+3]};
    float4 v10 = {o10[4*b2+0], o10[4*b2+1], o10[4*b2+2], o10[4*b2+3]};
    float4 v11 = {o11[4*b2+0], o11[4*b2+1], o11[4*b2+2], o11[4*b2+3]};
    *(float4*)&opart[ob0 + d0]      = v00;
    *(float4*)&opart[ob0 + 32 + d0] = v01;
    *(float4*)&opart[ob1 + d0]      = v10;
    *(float4*)&opart[ob1 + 32 + d0] = v11;
  }
  if (h == 0) {
    mlpart[(size_t)split * SEQ + qg0] = make_float2(m0, l0);
    mlpart[(size_t)split * SEQ + qg1] = make_float2(m1, l1);
  }
}

// ---------------- combine split-K partials ----------------
__global__ __launch_bounds__(256) void combine_kernel(
    const float* __restrict__ opart, const float2* __restrict__ mlpart,
    float* __restrict__ out, int S)
{
  const int tid = threadIdx.x;
  const int row = blockIdx.x * 16 + (tid >> 4);
  const int c4  = tid & 15;
  float mstar = -3.0e38f;
  for (int i = 0; i < S; ++i)
    mstar = fmaxf(mstar, mlpart[(size_t)i * SEQ + row].x);
  float L = 0.f, ax = 0.f, ay = 0.f, az = 0.f, aw = 0.f;
  for (int i = 0; i < S; ++i) {
    float2 ml = mlpart[(size_t)i * SEQ + row];
    float  wgt = exp2f_fast(ml.x - mstar);
    L = fmaf(wgt, ml.y, L);
    float4 ov = ((const float4*)(opart + ((size_t)i * SEQ + row) * DOUT))[c4];
    ax = fmaf(wgt, ov.x, ax); ay = fmaf(wgt, ov.y, ay);
    az = fmaf(wgt, ov.z, az); aw = fmaf(wgt, ov.w, aw);
  }
  float inv = 1.0f / L;
  float4 res = {ax * inv, ay * inv, az * inv, aw * inv};
  ((float4*)(out + (size_t)row * DOUT))[c4] = res;
}

extern "C" void kernel_launch(void* const* d_in, const int* in_sizes, int n_in,
                              void* d_out, int out_size, void* d_ws, size_t ws_size,
                              hipStream_t stream)
{
  const float* x  = (const float*)d_in[0];
  const float* wq = (const float*)d_in[1];
  const float* wk = (const float*)d_in[2];
  const float* wv = (const float*)d_in[3];
  float* out = (float*)d_out;

  char* ws = (char*)d_ws;
  const size_t MB = (size_t)SEQ * DOUT * 2;   // 1 MB per bf16 [SEQ][64] array
  unsigned short* qhi  = (unsigned short*)(ws);
  unsigned short* qlo  = (unsigned short*)(ws + MB);
  unsigned short* khi  = (unsigned short*)(ws + 2 * MB);
  unsigned short* klo  = (unsigned short*)(ws + 3 * MB);
  unsigned short* vThi = (unsigned short*)(ws + 4 * MB);
  unsigned short* vTlo = (unsigned short*)(ws + 5 * MB);
  unsigned short* wThi = (unsigned short*)(ws + 6 * MB);            // 96 KB
  unsigned short* wTlo = (unsigned short*)(ws + 6 * MB + 131072);   // 96 KB
  float* opart = (float*)(ws + 7 * MB);

  int S = 16;
  while (S > 1) {
    size_t need = 7 * MB + ((size_t)S * SEQ * DOUT + (size_t)S * SEQ * 2) * 4;
    if (need <= ws_size) break;
    S >>= 1;
  }
  float2* mlpart = (float2*)(opart + (size_t)S * SEQ * DOUT);
  const int slice_len = SEQ / S;

  wconv_kernel<<<32, 256, 0, stream>>>(wq, wk, wv, wThi, wTlo);
  qkv_mfma_kernel<<<dim3(SEQ / 32, 3), 128, 0, stream>>>(
      x, wThi, wTlo, qhi, qlo, khi, klo, vThi, vTlo);
  attn_mfma_kernel<<<dim3(SEQ / 256, S), 256, 0, stream>>>(
      qhi, qlo, khi, klo, vThi, vTlo, opart, mlpart, slice_len);
  combine_kernel<<<SEQ / 16, 256, 0, stream>>>(opart, mlpart, out, S);
}